// Round 1
// baseline (3451.266 us; speedup 1.0000x reference)
//
#include <hip/hip_runtime.h>

#define T_STEPS 2048
#define NBATCH  1024
#define HID     32
#define G4      128   // 4*HID gate rows

__device__ __forceinline__ float sigm(float v) {
    return __builtin_amdgcn_rcpf(1.0f + __expf(-v));
}
__device__ __forceinline__ float tanh_fast(float v) {
    float xc = fminf(fmaxf(v, -15.0f), 15.0f);
    float e  = __expf(-2.0f * xc);
    return (1.0f - e) * __builtin_amdgcn_rcpf(1.0f + e);
}

// One block per batch element. 128 threads: thread g owns gate-row g
// (i: 0..31, f: 32..63, g: 64..95, o: 96..127) of all three layers.
// Weight rows in registers (160 VGPRs); h vectors in LDS (broadcast reads).
__global__ __launch_bounds__(128, 2)
void lstm3_fc_kernel(const float* __restrict__ x,
                     const float* __restrict__ Wih0, const float* __restrict__ Whh0,
                     const float* __restrict__ bih0, const float* __restrict__ bhh0,
                     const float* __restrict__ Wih1, const float* __restrict__ Whh1,
                     const float* __restrict__ bih1, const float* __restrict__ bhh1,
                     const float* __restrict__ Wih2, const float* __restrict__ Whh2,
                     const float* __restrict__ bih2, const float* __restrict__ bhh2,
                     const float* __restrict__ Wfc,  const float* __restrict__ bfc,
                     float* __restrict__ out)
{
    const int g = threadIdx.x;   // 0..127
    const int b = blockIdx.x;    // 0..1023

    // ---- load per-thread weight rows into registers ----
    float whh0[HID], wih1[HID], whh1[HID], wih2[HID], whh2[HID];
    {
        const float4* p0 = (const float4*)(Whh0 + g * HID);
        const float4* p1 = (const float4*)(Wih1 + g * HID);
        const float4* p2 = (const float4*)(Whh1 + g * HID);
        const float4* p3 = (const float4*)(Wih2 + g * HID);
        const float4* p4 = (const float4*)(Whh2 + g * HID);
#pragma unroll
        for (int q = 0; q < 8; ++q) {
            float4 v0 = p0[q];
            float4 v1 = p1[q];
            float4 v2 = p2[q];
            float4 v3 = p3[q];
            float4 v4 = p4[q];
            whh0[4*q+0] = v0.x; whh0[4*q+1] = v0.y; whh0[4*q+2] = v0.z; whh0[4*q+3] = v0.w;
            wih1[4*q+0] = v1.x; wih1[4*q+1] = v1.y; wih1[4*q+2] = v1.z; wih1[4*q+3] = v1.w;
            whh1[4*q+0] = v2.x; whh1[4*q+1] = v2.y; whh1[4*q+2] = v2.z; whh1[4*q+3] = v2.w;
            wih2[4*q+0] = v3.x; wih2[4*q+1] = v3.y; wih2[4*q+2] = v3.z; wih2[4*q+3] = v3.w;
            whh2[4*q+0] = v4.x; whh2[4*q+1] = v4.y; whh2[4*q+2] = v4.z; whh2[4*q+3] = v4.w;
        }
    }
    const float wih0g = Wih0[g];              // Wih0 is (128,1)
    const float bias0 = bih0[g] + bhh0[g];
    const float bias1 = bih1[g] + bhh1[g];
    const float bias2 = bih2[g] + bhh2[g];
    const float wfcg  = (g < HID) ? Wfc[g] : 0.0f;
    const float bfc0  = bfc[0];

    __shared__ __align__(16) float H0[HID];
    __shared__ __align__(16) float H1[HID];
    __shared__ __align__(16) float H2[HID];
    __shared__ float GT[G4];

    if (g < HID) { H0[g] = 0.0f; H1[g] = 0.0f; H2[g] = 0.0f; }
    float c0 = 0.0f, c1 = 0.0f, c2 = 0.0f;
    __syncthreads();

    float xt = x[b];   // x[t=0][b]
    for (int t = 0; t < T_STEPS; ++t) {
        // prefetch next step's x early; latency hides under this step's work
        const int tn = (t + 1 < T_STEPS) ? (t + 1) : (T_STEPS - 1);
        const float xnext = x[tn * NBATCH + b];

        // ================= layer 0 =================
        float acc = fmaf(wih0g, xt, bias0);
#pragma unroll
        for (int q = 0; q < 8; ++q) {
            float4 h = ((const float4*)H0)[q];
            acc = fmaf(whh0[4*q+0], h.x, acc);
            acc = fmaf(whh0[4*q+1], h.y, acc);
            acc = fmaf(whh0[4*q+2], h.z, acc);
            acc = fmaf(whh0[4*q+3], h.w, acc);
        }
        GT[g] = acc;
        __syncthreads();
        if (g < HID) {
            float ii = sigm(GT[g]);
            float ff = sigm(GT[HID + g]);
            float gg = tanh_fast(GT[2*HID + g]);
            float oo = sigm(GT[3*HID + g]);
            c0 = fmaf(ff, c0, ii * gg);
            H0[g] = oo * tanh_fast(c0);
        }
        __syncthreads();

        // ================= layer 1 =================
        acc = bias1;
#pragma unroll
        for (int q = 0; q < 8; ++q) {
            float4 a = ((const float4*)H0)[q];   // h0 (new)
            float4 h = ((const float4*)H1)[q];   // h1 (old)
            acc = fmaf(wih1[4*q+0], a.x, acc);
            acc = fmaf(wih1[4*q+1], a.y, acc);
            acc = fmaf(wih1[4*q+2], a.z, acc);
            acc = fmaf(wih1[4*q+3], a.w, acc);
            acc = fmaf(whh1[4*q+0], h.x, acc);
            acc = fmaf(whh1[4*q+1], h.y, acc);
            acc = fmaf(whh1[4*q+2], h.z, acc);
            acc = fmaf(whh1[4*q+3], h.w, acc);
        }
        GT[g] = acc;
        __syncthreads();
        if (g < HID) {
            float ii = sigm(GT[g]);
            float ff = sigm(GT[HID + g]);
            float gg = tanh_fast(GT[2*HID + g]);
            float oo = sigm(GT[3*HID + g]);
            c1 = fmaf(ff, c1, ii * gg);
            H1[g] = oo * tanh_fast(c1);
        }
        __syncthreads();

        // ================= layer 2 =================
        acc = bias2;
#pragma unroll
        for (int q = 0; q < 8; ++q) {
            float4 a = ((const float4*)H1)[q];   // h1 (new)
            float4 h = ((const float4*)H2)[q];   // h2 (old)
            acc = fmaf(wih2[4*q+0], a.x, acc);
            acc = fmaf(wih2[4*q+1], a.y, acc);
            acc = fmaf(wih2[4*q+2], a.z, acc);
            acc = fmaf(wih2[4*q+3], a.w, acc);
            acc = fmaf(whh2[4*q+0], h.x, acc);
            acc = fmaf(whh2[4*q+1], h.y, acc);
            acc = fmaf(whh2[4*q+2], h.z, acc);
            acc = fmaf(whh2[4*q+3], h.w, acc);
        }
        GT[g] = acc;
        __syncthreads();
        if (g < HID) {
            float ii = sigm(GT[g]);
            float ff = sigm(GT[HID + g]);
            float gg = tanh_fast(GT[2*HID + g]);
            float oo = sigm(GT[3*HID + g]);
            c2 = fmaf(ff, c2, ii * gg);
            float hh = oo * tanh_fast(c2);
            H2[g] = hh;
            // fused FC: out[t][b] = sum_j h2[j]*Wfc[j] + bfc
            float v = hh * wfcg;
            v += __shfl_xor(v, 16);
            v += __shfl_xor(v, 8);
            v += __shfl_xor(v, 4);
            v += __shfl_xor(v, 2);
            v += __shfl_xor(v, 1);
            if (g == 0) out[t * NBATCH + b] = v + bfc0;
        }
        __syncthreads();

        xt = xnext;
    }
}

extern "C" void kernel_launch(void* const* d_in, const int* in_sizes, int n_in,
                              void* d_out, int out_size, void* d_ws, size_t ws_size,
                              hipStream_t stream)
{
    const float* x    = (const float*)d_in[0];
    const float* Wih0 = (const float*)d_in[1];
    const float* Whh0 = (const float*)d_in[2];
    const float* bih0 = (const float*)d_in[3];
    const float* bhh0 = (const float*)d_in[4];
    const float* Wih1 = (const float*)d_in[5];
    const float* Whh1 = (const float*)d_in[6];
    const float* bih1 = (const float*)d_in[7];
    const float* bhh1 = (const float*)d_in[8];
    const float* Wih2 = (const float*)d_in[9];
    const float* Whh2 = (const float*)d_in[10];
    const float* bih2 = (const float*)d_in[11];
    const float* bhh2 = (const float*)d_in[12];
    const float* Wfc  = (const float*)d_in[13];
    const float* bfc  = (const float*)d_in[14];
    float* out        = (float*)d_out;

    lstm3_fc_kernel<<<dim3(NBATCH), dim3(G4), 0, stream>>>(
        x, Wih0, Whh0, bih0, bhh0,
        Wih1, Whh1, bih1, bhh1,
        Wih2, Whh2, bih2, bhh2,
        Wfc, bfc, out);
}